// Round 1
// baseline (212.053 us; speedup 1.0000x reference)
//
#include <hip/hip_runtime.h>

// Problem constants (match the reference's module-level B, C, H, W, L)
#define B_  8
#define C_  32
#define HW_ (512 * 512)
#define L_  512

#define PIX_PER_BLOCK 4096
#define THREADS       256
#define BLOCKS_PER_B  (HW_ / PIX_PER_BLOCK)   // 64

// One block: batch b, 4096-pixel chunk, all 32 channels.
// LDS: [C][L] fp32 accumulator = 64 KiB -> 2 blocks/CU on MI355X (160 KiB LDS).
__global__ __launch_bounds__(THREADS, 2)
void vline_pool_kernel(const float* __restrict__ input,      // [B,C,H,W]
                       const int*   __restrict__ indmap,     // [B,H,W]
                       const int*   __restrict__ out_count,  // [B,L]
                       const int*   __restrict__ valid,      // [B,H,W]
                       float*       __restrict__ out)        // [B,C,L]
{
    __shared__ float acc[C_ * L_];   // 64 KiB

    const int bid   = blockIdx.x;
    const int b     = bid / BLOCKS_PER_B;
    const int chunk = bid % BLOCKS_PER_B;
    const int t     = threadIdx.x;

    // Zero the LDS accumulator
    #pragma unroll
    for (int i = t; i < C_ * L_; i += THREADS) acc[i] = 0.0f;
    __syncthreads();

    const int      pbase = chunk * PIX_PER_BLOCK;
    const int*     im    = indmap + (long long)b * HW_ + pbase;
    const int*     vm    = valid  + (long long)b * HW_ + pbase;
    const float*   inp   = input  + (long long)b * C_ * HW_ + pbase;

    // Each thread handles 4 consecutive pixels per iteration (float4/int4 loads).
    // PIX_PER_BLOCK / (THREADS*4) = 4 iterations.
    for (int it = 0; it < PIX_PER_BLOCK / (THREADS * 4); ++it) {
        const int p0 = it * (THREADS * 4) + t * 4;
        const int4 idx = *reinterpret_cast<const int4*>(im + p0);
        const int4 v   = *reinterpret_cast<const int4*>(vm + p0);

        #pragma unroll 4
        for (int c = 0; c < C_; ++c) {
            const float4 x = *reinterpret_cast<const float4*>(inp + (long long)c * HW_ + p0);
            if (v.x) atomicAdd(&acc[c * L_ + idx.x], x.x);
            if (v.y) atomicAdd(&acc[c * L_ + idx.y], x.y);
            if (v.z) atomicAdd(&acc[c * L_ + idx.z], x.z);
            if (v.w) atomicAdd(&acc[c * L_ + idx.w], x.w);
        }
    }
    __syncthreads();

    // Flush: partial / count  ->  global atomicAdd into out[b][c][l].
    // (sum/cnt == sum of partial/cnt, so the divide can be fused here.)
    const int*  cnt = out_count + b * L_;
    float*      ob  = out + (long long)b * C_ * L_;
    for (int e = t; e < C_ * L_; e += THREADS) {
        const int   l   = e & (L_ - 1);
        const float val = acc[e];
        if (val != 0.0f) {
            atomicAdd(&ob[e], val / (float)cnt[l]);
        }
    }
}

extern "C" void kernel_launch(void* const* d_in, const int* in_sizes, int n_in,
                              void* d_out, int out_size, void* d_ws, size_t ws_size,
                              hipStream_t stream) {
    const float* input     = (const float*)d_in[0];   // [B,C,H,W] fp32
    const int*   indmap    = (const int*)  d_in[1];   // [B,H,W]
    const int*   out_count = (const int*)  d_in[2];   // [B,L]
    const int*   valid     = (const int*)  d_in[3];   // [B,H,W]
    float*       out       = (float*)      d_out;     // [B,C,L]

    // Harness poisons d_out with 0xAA and never re-zeroes between replays.
    hipMemsetAsync(d_out, 0, (size_t)out_size * sizeof(float), stream);

    dim3 grid(B_ * BLOCKS_PER_B);   // 512 blocks = 2 per CU, all co-resident
    vline_pool_kernel<<<grid, THREADS, 0, stream>>>(input, indmap, out_count, valid, out);
}